// Round 2
// baseline (279.848 us; speedup 1.0000x reference)
//
#include <hip/hip_runtime.h>
#include <hip/hip_bf16.h>

typedef __hip_bfloat16 bf16;
typedef __attribute__((ext_vector_type(8))) short short8v;          // 8 bf16 (4 VGPRs)
typedef __attribute__((ext_vector_type(8))) unsigned short ushort8v;
typedef __attribute__((ext_vector_type(4))) unsigned short ushort4v;
typedef __attribute__((ext_vector_type(4))) float float4v;

__device__ __forceinline__ float bfu2f(unsigned short u) {
    union { unsigned int i; float f; } v; v.i = ((unsigned int)u) << 16; return v.f;
}
__device__ __forceinline__ unsigned short f2bfu_rn(float x) {
    union { float f; unsigned int i; } u; u.f = x;
    unsigned int r = (u.i + 0x7FFFu + ((u.i >> 16) & 1u)) >> 16;
    return (unsigned short)r;
}

// ---------- cast+transpose weights: W[k][n] fp32 -> Wt[n][k] bf16. grid (4,4,4) ----------
__global__ __launch_bounds__(256) void cast_wt(
    const float* __restrict__ Wq, const float* __restrict__ Wk,
    const float* __restrict__ Wv, const float* __restrict__ Wp,
    unsigned short* __restrict__ wt)
{
    __shared__ unsigned short tile[64][72];
    const float* W = (blockIdx.z == 0) ? Wq : (blockIdx.z == 1) ? Wk
                   : (blockIdx.z == 2) ? Wv : Wp;
    unsigned short* WT = wt + (size_t)blockIdx.z * 65536;
    const int t = threadIdx.x;
    const int k0 = blockIdx.x * 64, n0 = blockIdx.y * 64;
    {
        const int r = t >> 2, cseg = (t & 3) * 16;
        const float* src = W + (size_t)(k0 + r) * 256 + n0 + cseg;
        #pragma unroll
        for (int j = 0; j < 16; ++j) tile[r][cseg + j] = f2bfu_rn(src[j]);
    }
    __syncthreads();
    {
        const int ch = t & 63, lq = t >> 6;
        ushort8v o0, o1;
        #pragma unroll
        for (int i = 0; i < 8; ++i) o0[i] = tile[lq * 16 + i][ch];
        #pragma unroll
        for (int i = 0; i < 8; ++i) o1[i] = tile[lq * 16 + 8 + i][ch];
        unsigned short* dst = WT + (size_t)(n0 + ch) * 256 + k0 + lq * 16;
        *(ushort8v*)(dst)     = o0;
        *(ushort8v*)(dst + 8) = o1;
    }
}

// ---------- fused q/k/v projections, 16-row blocks for 2x occupancy. ----------
// grid 1382: [0,38) q, [38,710) k, [710,1382) v. 4 waves x 64 cols each.
__global__ __launch_bounds__(256) void proj_all(
    const float* __restrict__ q, const float* __restrict__ k, const float* __restrict__ v,
    const unsigned short* __restrict__ wt,
    unsigned short* __restrict__ qb, unsigned short* __restrict__ kb,
    unsigned short* __restrict__ vt)
{
    const int t = threadIdx.x;
    const int wave = t >> 6, lane = t & 63;
    const int m16 = lane & 15, quad = lane >> 4;
    const int nc0 = wave * 64;
    const int bx = blockIdx.x;

    const float* A; const unsigned short* Wt; int m0, mode;
    if (bx < 38)       { mode = 0; m0 = bx * 16;         A = q; Wt = wt; }
    else if (bx < 710) { mode = 1; m0 = (bx - 38) * 16;  A = k; Wt = wt + 65536; }
    else               { mode = 2; m0 = (bx - 710) * 16; A = v; Wt = wt + 131072; }

    const int arow = (mode == 0) ? min(m0 + m16, 599) : (m0 + m16);
    const float* aptr = A + (size_t)arow * 256 + quad * 8;

    float4v acc[4];
    #pragma unroll
    for (int i = 0; i < 4; ++i) acc[i] = (float4v){0.f, 0.f, 0.f, 0.f};

    #pragma unroll
    for (int ks = 0; ks < 8; ++ks) {
        float4 a0 = *(const float4*)(aptr + ks * 32);
        float4 a1 = *(const float4*)(aptr + ks * 32 + 4);
        short8v af;
        af[0] = (short)f2bfu_rn(a0.x); af[1] = (short)f2bfu_rn(a0.y);
        af[2] = (short)f2bfu_rn(a0.z); af[3] = (short)f2bfu_rn(a0.w);
        af[4] = (short)f2bfu_rn(a1.x); af[5] = (short)f2bfu_rn(a1.y);
        af[6] = (short)f2bfu_rn(a1.z); af[7] = (short)f2bfu_rn(a1.w);
        #pragma unroll
        for (int i = 0; i < 4; ++i) {
            short8v bfr = *(const short8v*)(Wt + (size_t)(nc0 + i * 16 + m16) * 256 + ks * 32 + quad * 8);
            acc[i] = __builtin_amdgcn_mfma_f32_16x16x32_bf16(af, bfr, acc[i], 0, 0, 0);
        }
    }

    if (mode == 0) {
        #pragma unroll
        for (int i = 0; i < 4; ++i)
            #pragma unroll
            for (int r = 0; r < 4; ++r) {
                int m = m0 + quad * 4 + r;
                if (m < 600)
                    qb[(size_t)m * 256 + nc0 + i * 16 + m16] = f2bfu_rn(acc[i][r]);
            }
    } else if (mode == 1) {
        #pragma unroll
        for (int i = 0; i < 4; ++i)
            #pragma unroll
            for (int r = 0; r < 4; ++r) {
                int m = m0 + quad * 4 + r;
                kb[(size_t)m * 256 + nc0 + i * 16 + m16] = f2bfu_rn(acc[i][r]);
            }
    } else {
        const int bb = (m0 >= 5376) ? 1 : 0;
        const int lcol = m0 - bb * 5376 + quad * 4;
        #pragma unroll
        for (int i = 0; i < 4; ++i) {
            const int ch = nc0 + i * 16 + m16;
            ushort4v p;
            #pragma unroll
            for (int r = 0; r < 4; ++r) p[r] = f2bfu_rn(acc[i][r]);
            *(ushort4v*)(vt + (size_t)(bb * 256 + ch) * 5376 + lcol) = p;
        }
    }
}

// ---------- fused QK + softmax + PV + mask-field fold. wave = head. ----------
// grid 1600 (pad of 1596 = 2b x 42zz x 19nt), 128 l per block. Level is uniform
// per block (zz<32 -> f1, 32..39 -> f2, else f3) so the fold has no per-pixel
// branches and weights live in a transposed 64-float LDS array read as two
// broadcast float4s per hh. probs stride 136 u16 = 272 B: 16B-aligned rows,
// conflict-free ds_read_b128 in PV. 34.8 KB LDS + launch_bounds(512,8)
// -> 4 blocks/CU = 32 waves/CU.
__global__ __launch_bounds__(512, 8) void attn_fused(
    const unsigned short* __restrict__ qb, const unsigned short* __restrict__ kb,
    const unsigned short* __restrict__ vt,
    const float* __restrict__ W1, const float* __restrict__ b1,
    const float* __restrict__ W2, const float* __restrict__ b2,
    const float* __restrict__ W3, const float* __restrict__ b3,
    const float* __restrict__ Wm,
    float* __restrict__ xbp, float* __restrict__ Sp,
    float* __restrict__ g2, float* __restrict__ g3, float* __restrict__ maskp)
{
    __shared__ unsigned short probs[8][16 * 136];   // 34,816 B
    __shared__ float wT[64];                        // wT[hh*8+hp] = Wl[hp*8+hh]
    __shared__ float blv[8], wmv[8];

    const int t = threadIdx.x;
    const int wave = t >> 6, lane = t & 63;

    // XCD-grouped decode: block i0 -> XCD i0&7 owns 200 consecutive m values
    const int i0 = blockIdx.x;
    const int m = (i0 & 7) * 200 + (i0 >> 3);
    if (m >= 1596) return;
    const int grp = m / 19, nt = m - grp * 19;
    const int b = grp / 42, zz = grp - b * 42;
    const int n0 = nt * 16;
    const int l0 = zz * 128;
    const int lvl = (zz >= 32) + (zz >= 40);

    const float* Wl = (lvl == 0) ? W1 : (lvl == 1) ? W2 : W3;
    const float* bl = (lvl == 0) ? b1 : (lvl == 1) ? b2 : b3;
    if (t < 64) wT[t] = Wl[(t & 7) * 8 + (t >> 3)];
    if (t < 8)  { blv[t] = bl[t]; wmv[t] = Wm[lvl * 8 + t]; }

    const int m16 = lane & 15, quad = lane >> 4;
    const int h = wave;                 // wave = head
    const float scale = 0.17677669529663687f;   // 1/sqrt(32)

    const short8v qfrag = *(const short8v*)(qb + (size_t)(b * 300 + min(n0 + m16, 299)) * 256 + h * 32 + quad * 8);
    const unsigned short* kbase = kb + (size_t)(b * 5376 + l0) * 256 + h * 32 + quad * 8;
    const unsigned short* vt0 = vt + (size_t)(b * 256 + h * 32 + m16) * 5376 + l0;
    const unsigned short* vt1 = vt0 + (size_t)16 * 5376;
    unsigned short* pw = &probs[wave][0];

    // ---- QK: 8 tiles of 16 l. A = k (m=l), B = q (n=n). C: row=l, col=n.
    #pragma unroll
    for (int i = 0; i < 8; ++i) {
        short8v kf = *(const short8v*)(kbase + (size_t)(i * 16 + m16) * 256);
        float4v c = {0.f, 0.f, 0.f, 0.f};
        c = __builtin_amdgcn_mfma_f32_16x16x32_bf16(kf, qfrag, c, 0, 0, 0);
        ushort4v pk;
        #pragma unroll
        for (int r = 0; r < 4; ++r) pk[r] = f2bfu_rn(c[r] * scale);
        *(ushort4v*)(pw + m16 * 136 + i * 16 + quad * 4) = pk;
    }
    __syncthreads();   // all 8 heads' logits visible (also fences wT/blv/wmv)

    // ---- mask-field fold: 16 n x 128 l, 4 px/thread, uniform level
    {
        const int nl = t >> 5;              // 0..15
        const int n = n0 + nl;
        if (n < 300) {
            const int lb = (t & 31) * 4;
            ushort4v u[8];
            #pragma unroll
            for (int hp = 0; hp < 8; ++hp)
                u[hp] = *(const ushort4v*)(&probs[hp][nl * 136 + lb]);
            float sv[4][8];
            #pragma unroll
            for (int pp = 0; pp < 4; ++pp)
                #pragma unroll
                for (int hp = 0; hp < 8; ++hp) sv[pp][hp] = bfu2f(u[hp][pp]);
            float facc[4] = {0.f, 0.f, 0.f, 0.f};
            #pragma unroll
            for (int hh = 0; hh < 8; ++hh) {
                const float4 wA = *(const float4*)(&wT[hh * 8]);
                const float4 wB = *(const float4*)(&wT[hh * 8 + 4]);
                const float bb_ = blv[hh], wm_ = wmv[hh];
                #pragma unroll
                for (int pp = 0; pp < 4; ++pp) {
                    float f = bb_
                        + sv[pp][0] * wA.x + sv[pp][1] * wA.y
                        + sv[pp][2] * wA.z + sv[pp][3] * wA.w
                        + sv[pp][4] * wB.x + sv[pp][5] * wB.y
                        + sv[pp][6] * wB.z + sv[pp][7] * wB.w;
                    facc[pp] += fmaxf(f, 0.f) * wm_;
                }
            }
            float4 o;
            o.x = facc[0]; o.y = facc[1]; o.z = facc[2]; o.w = facc[3];
            const size_t bn = (size_t)(b * 300 + n);
            float* dst = (lvl == 0) ? maskp + bn * 4096 + l0 + lb
                       : (lvl == 1) ? g2 + bn * 1024 + (l0 - 4096) + lb
                       :              g3 + bn * 256  + (l0 - 5120) + lb;
            *(float4*)dst = o;
        }
    }

    // ---- PV: 4 K-steps of 32 l. A[m=n=m16][k=l], exp on read.
    float4v c0 = {0.f, 0.f, 0.f, 0.f};
    float4v c1 = {0.f, 0.f, 0.f, 0.f};
    float sm = 0.f;
    #pragma unroll
    for (int step = 0; step < 4; ++step) {
        const int lloc = step * 32 + quad * 8;
        ushort8v ua = *(const ushort8v*)(pw + m16 * 136 + lloc);
        short8v af;
        #pragma unroll
        for (int j = 0; j < 8; ++j) {
            float e = __expf(bfu2f(ua[j]));
            sm += e;
            af[j] = (short)f2bfu_rn(e);
        }
        short8v bb0 = *(const short8v*)(vt0 + lloc);
        short8v bb1 = *(const short8v*)(vt1 + lloc);
        c0 = __builtin_amdgcn_mfma_f32_16x16x32_bf16(af, bb0, c0, 0, 0, 0);
        c1 = __builtin_amdgcn_mfma_f32_16x16x32_bf16(af, bb1, c1, 0, 0, 0);
    }

    // ---- per-wave (= per-head) direct stores
    sm += __shfl_xor(sm, 16);
    sm += __shfl_xor(sm, 32);
    float* xplane = xbp + (size_t)zz * 153600;
    float* splane = Sp + (size_t)zz * 4800;
    if (lane < 16 && n0 + lane < 300)
        splane[(size_t)(b * 300 + n0 + lane) * 8 + h] = sm;
    #pragma unroll
    for (int r = 0; r < 4; ++r) {
        const int n = n0 + quad * 4 + r;
        if (n < 300) {
            float* o = xplane + (size_t)(b * 300 + n) * 256 + h * 32 + m16;
            o[0]  = c0[r];
            o[16] = c1[r];
        }
    }
}

// ---------- finish: blocks [0,600) mask combine (bilinear+relu, in-place on
// maskpart); blocks [600,755) reduce 42 xbp planes -> xr and Sp -> Sr.
__global__ __launch_bounds__(256) void finish(
    const float* __restrict__ g2, const float* __restrict__ g3,
    const float* __restrict__ xbp, const float* __restrict__ Sp,
    float* __restrict__ xr, float* __restrict__ Sr,
    const float* __restrict__ bmp, float* __restrict__ out)
{
    const int t = threadIdx.x;
    if (blockIdx.x < 600) {
        __shared__ float gs[1280];      // g2s [0,1024), g3s [1024,1280)
        __shared__ float bms;
        const int bn = blockIdx.x;
        if (t == 0) bms = bmp[0];
        ((float4v*)gs)[t] = ((const float4v*)(g2 + (size_t)bn * 1024))[t];
        if (t < 64) ((float4v*)(gs + 1024))[t] = ((const float4v*)(g3 + (size_t)bn * 256))[t];
        __syncthreads();

        float* mp = out + 153600 + (size_t)bn * 4096;
        #pragma unroll
        for (int it = 0; it < 4; ++it) {
            const int p0 = it * 1024 + t * 4;
            float4v mv = *(const float4v*)(mp + p0);
            float4v res;
            #pragma unroll
            for (int pp = 0; pp < 4; ++pp) {
                const int p = p0 + pp;
                const int Y = p >> 6, X = p & 63;
                float acc = mv[pp] + bms;
                {   // g2 bilinear 32 -> 64
                    float ry = fminf(fmaxf(0.5f * Y - 0.25f, 0.f), 31.f);
                    float rx = fminf(fmaxf(0.5f * X - 0.25f, 0.f), 31.f);
                    int y0 = (int)ry, x0 = (int)rx;
                    int y1 = min(y0 + 1, 31), x1 = min(x0 + 1, 31);
                    float wy = ry - (float)y0, wx = rx - (float)x0;
                    acc += (gs[y0 * 32 + x0] * (1.f - wx) + gs[y0 * 32 + x1] * wx) * (1.f - wy)
                         + (gs[y1 * 32 + x0] * (1.f - wx) + gs[y1 * 32 + x1] * wx) * wy;
                }
                {   // g3 bilinear 16 -> 64
                    float ry = fminf(fmaxf(0.25f * Y - 0.375f, 0.f), 15.f);
                    float rx = fminf(fmaxf(0.25f * X - 0.375f, 0.f), 15.f);
                    int y0 = (int)ry, x0 = (int)rx;
                    int y1 = min(y0 + 1, 15), x1 = min(x0 + 1, 15);
                    float wy = ry - (float)y0, wx = rx - (float)x0;
                    acc += (gs[1024 + y0 * 16 + x0] * (1.f - wx) + gs[1024 + y0 * 16 + x1] * wx) * (1.f - wy)
                         + (gs[1024 + y1 * 16 + x0] * (1.f - wx) + gs[1024 + y1 * 16 + x1] * wx) * wy;
                }
                res[pp] = fmaxf(acc, 0.f);
            }
            *(float4v*)(mp + p0) = res;
        }
    } else {
        const int idx = (blockIdx.x - 600) * 256 + t;   // float4 index
        if (idx < 38400) {
            float4v s = {0.f, 0.f, 0.f, 0.f};
            #pragma unroll 7
            for (int z = 0; z < 42; ++z)
                s += *(const float4v*)(xbp + (size_t)z * 153600 + (size_t)idx * 4);
            *(float4v*)(xr + (size_t)idx * 4) = s;
        } else if (idx < 38400 + 1200) {
            const int si = (idx - 38400) * 4;
            float4v s = {0.f, 0.f, 0.f, 0.f};
            #pragma unroll 7
            for (int z = 0; z < 42; ++z)
                s += *(const float4v*)(Sp + (size_t)z * 4800 + si);
            *(float4v*)(Sr + si) = s;
        }
    }
}

// ---------- output projection on reduced plane + 1/S. grid 38, 16 rows ----------
__global__ __launch_bounds__(256) void proj_out(
    const float* __restrict__ xr, const float* __restrict__ Sr,
    const unsigned short* __restrict__ Wtp,
    const float* __restrict__ bpv, float* __restrict__ out)
{
    const int t = threadIdx.x;
    const int wave = t >> 6, lane = t & 63;
    const int m16 = lane & 15, quad = lane >> 4;
    const int nc0 = wave * 64;
    const int m0 = blockIdx.x * 16;
    const int arow = min(m0 + m16, 599);
    const float* a0p = xr + (size_t)arow * 256 + quad * 8;

    float4v acc[4];
    #pragma unroll
    for (int i = 0; i < 4; ++i) acc[i] = (float4v){0.f, 0.f, 0.f, 0.f};

    #pragma unroll
    for (int ks = 0; ks < 8; ++ks) {
        const float rS = 1.0f / Sr[(size_t)arow * 8 + ks];
        float4 x0 = *(const float4*)(a0p + ks * 32);
        float4 x1 = *(const float4*)(a0p + ks * 32 + 4);
        short8v af;
        af[0] = (short)f2bfu_rn(x0.x * rS); af[1] = (short)f2bfu_rn(x0.y * rS);
        af[2] = (short)f2bfu_rn(x0.z * rS); af[3] = (short)f2bfu_rn(x0.w * rS);
        af[4] = (short)f2bfu_rn(x1.x * rS); af[5] = (short)f2bfu_rn(x1.y * rS);
        af[6] = (short)f2bfu_rn(x1.z * rS); af[7] = (short)f2bfu_rn(x1.w * rS);
        #pragma unroll
        for (int i = 0; i < 4; ++i) {
            short8v bfr = *(const short8v*)(Wtp + (size_t)(nc0 + i * 16 + m16) * 256 + ks * 32 + quad * 8);
            acc[i] = __builtin_amdgcn_mfma_f32_16x16x32_bf16(af, bfr, acc[i], 0, 0, 0);
        }
    }

    #pragma unroll
    for (int i = 0; i < 4; ++i) {
        const float bv = bpv[nc0 + i * 16 + m16];
        #pragma unroll
        for (int r = 0; r < 4; ++r) {
            int mm = m0 + quad * 4 + r;
            if (mm < 600)
                out[(size_t)mm * 256 + nc0 + i * 16 + m16] = acc[i][r] + bv;
        }
    }
}

// ---------- launch ----------
extern "C" void kernel_launch(void* const* d_in, const int* in_sizes, int n_in,
                              void* d_out, int out_size, void* d_ws, size_t ws_size,
                              hipStream_t stream) {
    const float* query = (const float*)d_in[0];
    const float* key   = (const float*)d_in[1];
    const float* value = (const float*)d_in[2];
    const float* Wq = (const float*)d_in[5];
    const float* Wk = (const float*)d_in[6];
    const float* Wv = (const float*)d_in[7];
    const float* Wp = (const float*)d_in[8];
    const float* bp = (const float*)d_in[9];
    const float* W1 = (const float*)d_in[10];
    const float* b1 = (const float*)d_in[11];
    const float* W2 = (const float*)d_in[12];
    const float* b2 = (const float*)d_in[13];
    const float* W3 = (const float*)d_in[14];
    const float* b3 = (const float*)d_in[15];
    const float* Wm = (const float*)d_in[16];
    const float* bm = (const float*)d_in[17];
    float* out = (float*)d_out;

    char* ws = (char*)d_ws;
    unsigned short* wt = (unsigned short*)(ws);       // 524,288 B
    bf16*  qb   = (bf16*) (ws + 524288);              // 307,200 B
    bf16*  kb   = (bf16*) (ws + 831488);              // 5,505,024 B
    bf16*  vt   = (bf16*) (ws + 6336512);             // 5,505,024 B
    float* xbp  = (float*)(ws + 11841536);            // 42*600*256 fp32 = 25,804,800 B
    float* Sp   = (float*)(ws + 37646336);            // 42*4800 fp32    = 806,400 B
    float* g2   = (float*)(ws + 38452736);            // 600*1024 fp32   = 2,457,600 B
    float* g3   = (float*)(ws + 40910336);            // 600*256 fp32    = 614,400 B
    float* xr   = (float*)(ws + 41524736);            // 600*256 fp32    = 614,400 B
    float* Sr   = (float*)(ws + 42139136);            // 4800 fp32       = 19,200 B
    float* maskp = out + 153600;                      // level-1 fold written in-place

    cast_wt<<<dim3(4, 4, 4), 256, 0, stream>>>(Wq, Wk, Wv, Wp, wt);

    proj_all<<<1382, 256, 0, stream>>>(query, key, value, wt,
        (unsigned short*)qb, (unsigned short*)kb, (unsigned short*)vt);

    attn_fused<<<1600, 512, 0, stream>>>(
        (const unsigned short*)qb, (const unsigned short*)kb, (const unsigned short*)vt,
        W1, b1, W2, b2, W3, b3, Wm, xbp, Sp, g2, g3, maskp);

    finish<<<755, 256, 0, stream>>>(g2, g3, xbp, Sp, xr, Sr, bm, out);

    proj_out<<<38, 256, 0, stream>>>(xr, Sr, (const unsigned short*)wt + 196608, bp, out);
}